// Round 15
// baseline (54.439 us; speedup 1.0000x reference)
//
#include <hip/hip_runtime.h>
#include <hip/hip_bf16.h>

// Problem constants
#define B_ 2
#define C_ 256
#define O_ 256
#define T_ 16
#define H_ 64
#define W_ 64

typedef __bf16 bf16x8 __attribute__((ext_vector_type(8)));
typedef float  f32x4  __attribute__((ext_vector_type(4)));

// ws layout:
//   [0, 131072)       : W3d bf16 LINEAR image [256 o][256 c] (512 B rows)
//   [131072, 163840)  : obj f32 [b][t][o]
#define WS_OBJ_OFF 131072

// LDS-only barrier (r13): orders ds ops across waves without draining the
// vmem store queue.
__device__ __forceinline__ void barrier_lds_only() {
    asm volatile("s_waitcnt lgkmcnt(0)" ::: "memory");
    __builtin_amdgcn_s_barrier();
    asm volatile("" ::: "memory");
}

// ---------------- prep kernel (identical to r9/r12/r13) ----------------
__global__ __launch_bounds__(256) void prep_kernel(
    const float* __restrict__ fea_obj, const float* __restrict__ W3d,
    const float* __restrict__ W1d, const float* __restrict__ b1d,
    __bf16* __restrict__ wsW, float* __restrict__ wsObj) {
    const int bid = blockIdx.x;
    const int tid = threadIdx.x;
    if (bid < 32) {
        const int b = bid >> 4, t = bid & 15;
        __shared__ float fo[C_];
        fo[tid] = fea_obj[(b * C_ + tid) * T_ + t];
        __syncthreads();
        const int o = tid;
        const float4* wrow = (const float4*)(W1d + o * C_);
        float s = 0.f;
#pragma unroll 8
        for (int cq = 0; cq < C_ / 4; ++cq) {
            float4 wv = wrow[cq];
            s += wv.x * fo[cq * 4 + 0] + wv.y * fo[cq * 4 + 1] +
                 wv.z * fo[cq * 4 + 2] + wv.w * fo[cq * 4 + 3];
        }
        wsObj[(b * T_ + t) * O_ + o] = s + b1d[o];
    } else {
        const int g = (bid - 32) * 256 + tid;
        const int o = g >> 5;
        const int cg = g & 31;
        const float* sp = W3d + o * C_ + cg * 8;
        float4 a0 = *(const float4*)sp;
        float4 a1 = *(const float4*)(sp + 4);
        bf16x8 pk;
        pk[0] = (__bf16)a0.x; pk[1] = (__bf16)a0.y;
        pk[2] = (__bf16)a0.z; pk[3] = (__bf16)a0.w;
        pk[4] = (__bf16)a1.x; pk[5] = (__bf16)a1.y;
        pk[6] = (__bf16)a1.z; pk[7] = (__bf16)a1.w;
        *(bf16x8*)((char*)wsW + o * 512 + cg * 16) = pk;
    }
}

// ---------------- main kernel (r15: VGPR/LDS diet -> 3 blocks/CU) ----------
// Grid 1024 = mt(2) x wb(2) x hg(8) x bt(32). Block: 512 thr = 8 waves.
// Wave tile 16o x 32w: af[8] = 32 VGPR (was 64) -> steady live set ~62 regs,
// targeting the 6-waves/SIMD (84-VGPR) allocator budget implied by the
// 41KB static LDS (r4 mechanism). 2 panels of 16KB (barrier per h; r12
// showed the 2h/4-panel window was worth ~0). 3 blocks/CU = 24 waves/CU
// (was 16) -> fills the ~70% stall time of the latency-bound r13 plateau.
__global__ __attribute__((amdgpu_flat_work_group_size(512, 512),
                          amdgpu_waves_per_eu(6)))
void main_kernel(
    const float* __restrict__ fea_th, const float* __restrict__ fea_tw,
    const float* __restrict__ heatmap, const float* __restrict__ mask,
    const float* __restrict__ b3d,
    const __bf16* __restrict__ wsW, const float* __restrict__ wsObj,
    float* __restrict__ out) {
    __shared__ __align__(16) char smem[41984];
    // P0 = smem, P1 = smem+16384 : B panels [32 cg][32 w][16B]
    float* sTh  = (float*)(smem + 32768);    // [8 h][256 c] f32
    float* sPb  = (float*)(smem + 40960);    // [128] b3d (block's o-window)
    float* sObj = (float*)(smem + 41472);    // [128] obj (block's o-window)

    const int tid  = threadIdx.x;
    const int lane = tid & 63;
    const int wv   = tid >> 6;       // 0..7 -> o base o0 + wv*16
    const int kgrp = lane >> 4;
    const int l15  = lane & 15;

    const int bid = blockIdx.x;
    const int mt = bid & 1, wb = (bid >> 1) & 1;
    const int hg = (bid >> 2) & 7, bt = bid >> 5;
    const int b = bt >> 4, t = bt & 15;
    const int o0 = mt * 128, w0 = wb * 32, h0 = hg * 8;

    // ---- stage th (tid<256) and pb/obj (tid in [256,384)) ----
    const float* objp = wsObj + (b * T_ + t) * O_;
    if (tid < 256) {
        const float* thp = fea_th + ((b * C_ + tid) * T_ + t) * H_ + h0;
        float4 v0 = *(const float4*)thp;
        float4 v1 = *(const float4*)(thp + 4);
        sTh[0 * 256 + tid] = v0.x;  sTh[1 * 256 + tid] = v0.y;
        sTh[2 * 256 + tid] = v0.z;  sTh[3 * 256 + tid] = v0.w;
        sTh[4 * 256 + tid] = v1.x;  sTh[5 * 256 + tid] = v1.y;
        sTh[6 * 256 + tid] = v1.z;  sTh[7 * 256 + tid] = v1.w;
    } else if (tid < 384) {
        const int i = tid - 256;
        sPb[i]  = b3d[o0 + i];
        sObj[i] = objp[o0 + i];
    }

    // ---- tw -> per-thread bf16 slice (w = w0 + (tid&31), c in [cs,cs+16)) ----
    const int wl = tid & 31;
    const int cr = tid >> 5;          // 0..15
    const int cs = cr * 16;
    bf16x8 twb0, twb1;
    {
        const float* twp = fea_tw + ((b * C_ + cs) * T_ + t) * W_ + w0 + wl;
#pragma unroll
        for (int j = 0; j < 8; ++j) twb0[j] = (__bf16)twp[j * (T_ * W_)];
#pragma unroll
        for (int j = 0; j < 8; ++j) twb1[j] = (__bf16)twp[(8 + j) * (T_ * W_)];
    }

    // ---- A panel -> registers: af[ks], 32 VGPR (wave's 16o x 256c) ----
    bf16x8 af[8];
#pragma unroll
    for (int ks = 0; ks < 8; ++ks)
        af[ks] = *(const bf16x8*)(
            wsW + (o0 + wv * 16 + l15) * 256 + ks * 32 + kgrp * 8);

    // build: thread (wl, cr) -> cgs 2cr, 2cr+1; conflict-free contiguous
    const int wbyte = wl * 16;

    auto build = [&](int hl, char* dst) {
        const float* thp = sTh + hl * 256 + cs;
        const f32x4 t0 = *(const f32x4*)thp;
        const f32x4 t1 = *(const f32x4*)(thp + 4);
        const f32x4 t2 = *(const f32x4*)(thp + 8);
        const f32x4 t3 = *(const f32x4*)(thp + 12);
        bf16x8 z0, z1;
        z0[0] = (__bf16)((float)twb0[0] * t0[0]);
        z0[1] = (__bf16)((float)twb0[1] * t0[1]);
        z0[2] = (__bf16)((float)twb0[2] * t0[2]);
        z0[3] = (__bf16)((float)twb0[3] * t0[3]);
        z0[4] = (__bf16)((float)twb0[4] * t1[0]);
        z0[5] = (__bf16)((float)twb0[5] * t1[1]);
        z0[6] = (__bf16)((float)twb0[6] * t1[2]);
        z0[7] = (__bf16)((float)twb0[7] * t1[3]);
        z1[0] = (__bf16)((float)twb1[0] * t2[0]);
        z1[1] = (__bf16)((float)twb1[1] * t2[1]);
        z1[2] = (__bf16)((float)twb1[2] * t2[2]);
        z1[3] = (__bf16)((float)twb1[3] * t2[3]);
        z1[4] = (__bf16)((float)twb1[4] * t3[0]);
        z1[5] = (__bf16)((float)twb1[5] * t3[1]);
        z1[6] = (__bf16)((float)twb1[6] * t3[2]);
        z1[7] = (__bf16)((float)twb1[7] * t3[3]);
        *(bf16x8*)(dst + (2 * cr) * 512 + wbyte)     = z0;
        *(bf16x8*)(dst + (2 * cr + 1) * 512 + wbyte) = z1;
    };

    __syncthreads();          // sTh / sPb / sObj ready
    build(0, smem);
    __syncthreads();          // panel 0 ready

    const int hmb = (b * T_ + t) * (H_ * W_);
    const int ob  = wv * 16 + kgrp * 4;      // o offset within block window
    const int rb  = kgrp * 512 + l15 * 16;   // base of this lane's c-slice

    for (int hl = 0; hl < 8; ++hl) {
        char* cur = smem + ((hl & 1) ? 16384 : 0);
        char* nxt = smem + ((hl & 1) ? 0 : 16384);

        const int hglb = h0 + hl;
        const int hrow = hmb + hglb * W_ + w0 + l15;
        const float ht0 = heatmap[hrow],      mk0 = mask[hrow];
        const float ht1 = heatmap[hrow + 16], mk1 = mask[hrow + 16];

        f32x4 acc[2] = {};
#pragma unroll
        for (int ks = 0; ks < 8; ++ks) {
            const bf16x8 b0 = *(const bf16x8*)(cur + rb + ks * 2048);
            const bf16x8 b1 = *(const bf16x8*)(cur + rb + ks * 2048 + 256);
            acc[0] = __builtin_amdgcn_mfma_f32_16x16x32_bf16(af[ks], b0, acc[0], 0, 0, 0);
            acc[1] = __builtin_amdgcn_mfma_f32_16x16x32_bf16(af[ks], b1, acc[1], 0, 0, 0);
        }

        if (hl < 7) build(hl + 1, nxt);
        if (hl < 7) barrier_lds_only();   // LDS-only: stores keep flowing

        // ---- fused epilogue (r13-proven scalar-store form) ----
        const f32x4 pb4 = *(const f32x4*)(sPb + ob);
        const f32x4 po4 = *(const f32x4*)(sObj + ob);
#pragma unroll
        for (int r = 0; r < 4; ++r) {
            const int o = o0 + ob + r;
            float* orow = out + (((size_t)(b * O_ + o) * T_ + t) * H_ + hglb) * W_ + w0;
            float v0 = acc[0][r] + pb4[r];
            v0 = v0 * (1.f - ht0) + po4[r] * ht0;
            orow[l15] = v0 * mk0;
            float v1 = acc[1][r] + pb4[r];
            v1 = v1 * (1.f - ht1) + po4[r] * ht1;
            orow[16 + l15] = v1 * mk1;
        }
    }
}

extern "C" void kernel_launch(void* const* d_in, const int* in_sizes, int n_in,
                              void* d_out, int out_size, void* d_ws, size_t ws_size,
                              hipStream_t stream) {
    const float* fea_th  = (const float*)d_in[0];
    const float* fea_tw  = (const float*)d_in[1];
    const float* fea_obj = (const float*)d_in[2];
    const float* heatmap = (const float*)d_in[3];
    const float* mask    = (const float*)d_in[4];
    const float* W3d     = (const float*)d_in[5];
    const float* b3d     = (const float*)d_in[6];
    const float* W1d     = (const float*)d_in[7];
    const float* b1d     = (const float*)d_in[8];
    float* out = (float*)d_out;

    __bf16* wsW  = (__bf16*)d_ws;
    float* wsObj = (float*)((char*)d_ws + WS_OBJ_OFF);

    hipLaunchKernelGGL(prep_kernel, dim3(64), dim3(256), 0, stream,
                       fea_obj, W3d, W1d, b1d, wsW, wsObj);
    hipLaunchKernelGGL(main_kernel, dim3(1024), dim3(512), 0, stream,
                       fea_th, fea_tw, heatmap, mask, b3d, wsW, wsObj, out);
}